// Round 4
// baseline (2494.982 us; speedup 1.0000x reference)
//
#include <hip/hip_runtime.h>
#include <cmath>

#define BATCH    1048576
#define IN_DIM   16
#define ODE_DIM  64
#define OUT_DIM  16
#define N_STEPS  32

typedef _Float16 half2v __attribute__((ext_vector_type(2)));
typedef _Float16 half8v __attribute__((ext_vector_type(8)));
typedef float    f32x16 __attribute__((ext_vector_type(16)));
typedef unsigned u32x2  __attribute__((ext_vector_type(2)));
typedef unsigned u32x4  __attribute__((ext_vector_type(4)));

// 2*log2(e): MFMA output w = TANH_SCALE * s is both the exp2 argument of the
// fallback tanh (round-0 proven path) and the poly-tanh input domain.
#define TANH_SCALE 2.8853900817779268f

// ---------------------------------------------------------------------------
// tanh(s) ~= xc * P(v) with w = TANH_SCALE*s, xc = clamp(w,-PX,PX),
// v = (xc*CS)^2 - 1 in [-1,~0.998].  P: degree-PD, unit-weight LS fit at
// Chebyshev-in-w nodes (long double), cascade-rounded to f16.  A bit-exact
// host simulation of the device f16 pipeline validates; flag=1 -> device
// uses the round-0 exp2+rcp path instead.
// ---------------------------------------------------------------------------
#define PD 8
#define PX_F 11.83f      // TANH_SCALE * 4.1
#define CS_F 0.119507f   // ~= sqrt(2)/f16(PX_F), chosen slightly low

namespace {

static unsigned short f32_to_f16_rne(float ff) {
    unsigned u = __builtin_bit_cast(unsigned, ff);
    unsigned sign = (u >> 16) & 0x8000u;
    int exp = (int)((u >> 23) & 0xFF) - 127 + 15;
    unsigned man = u & 0x7FFFFFu;
    if (exp >= 31) return (unsigned short)(sign | 0x7C00u);
    if (exp <= 0) {
        if (exp < -10) return (unsigned short)sign;
        man |= 0x800000u;
        int shift = 14 - exp;
        unsigned half = man >> shift;
        unsigned rem  = man & ((1u << shift) - 1u);
        unsigned mid  = 1u << (shift - 1);
        if (rem > mid || (rem == mid && (half & 1u))) half++;
        return (unsigned short)(sign | half);
    }
    unsigned half = ((unsigned)exp << 10) | (man >> 13);
    unsigned rem = man & 0x1FFFu;
    if (rem > 0x1000u || (rem == 0x1000u && (half & 1u))) half++;
    return (unsigned short)(sign | half);
}

static unsigned short f32_to_f16_rtz(float ff) {   // chop (matches cvt_pkrtz)
    unsigned u = __builtin_bit_cast(unsigned, ff);
    unsigned sign = (u >> 16) & 0x8000u;
    unsigned e8 = (u >> 23) & 0xFFu;
    unsigned man = u & 0x7FFFFFu;
    if (e8 == 0xFFu) return (unsigned short)(sign | 0x7C00u | (man ? 0x200u : 0u));
    int exp = (int)e8 - 127 + 15;
    if (exp >= 31) return (unsigned short)(sign | 0x7BFFu);
    if (exp <= 0) {
        if (exp < -10) return (unsigned short)sign;
        man |= 0x800000u;
        return (unsigned short)(sign | (man >> (14 - exp)));
    }
    return (unsigned short)(sign | ((unsigned)exp << 10) | (man >> 13));
}

static float f16_to_f32h(unsigned short h) {
    unsigned sign = ((unsigned)h & 0x8000u) << 16;
    unsigned exp = (h >> 10) & 0x1Fu;
    unsigned man = h & 0x3FFu;
    unsigned u;
    if (exp == 0) {
        if (!man) u = sign;
        else {
            int e = -1;
            do { man <<= 1; ++e; } while (!(man & 0x400u));
            u = sign | ((unsigned)(127 - 15 - e) << 23) | ((man & 0x3FFu) << 13);
        }
    } else if (exp == 31) u = sign | 0x7F800000u | (man << 13);
    else u = sign | ((exp - 15 + 127) << 23) | (man << 13);
    return __builtin_bit_cast(float, u);
}

constexpr int FIT_N = 2001;
static long double g_xs[FIT_N], g_vs[FIT_N], g_tg[FIT_N];

// Unit-weight LS for c[0..nfree-1] with c[nfree..PD] held fixed.
static void ls_solve(int nfree, long double* c) {
    long double M[PD + 1][PD + 1] = {};
    long double rhs[PD + 1] = {};
    for (int i = 0; i < FIT_N; ++i) {
        long double pj[PD + 1];
        pj[0] = 1.0L;
        for (int j = 1; j <= PD; ++j) pj[j] = pj[j - 1] * g_vs[i];
        long double resid = g_tg[i];
        for (int j = nfree; j <= PD; ++j) resid -= g_xs[i] * pj[j] * c[j];
        for (int a = 0; a < nfree; ++a) {
            long double ba = g_xs[i] * pj[a];
            for (int b2 = 0; b2 < nfree; ++b2) M[a][b2] += ba * g_xs[i] * pj[b2];
            rhs[a] += ba * resid;
        }
    }
    for (int a = 0; a < nfree; ++a) {
        int piv = a;
        for (int r = a + 1; r < nfree; ++r)
            if (fabsl(M[r][a]) > fabsl(M[piv][a])) piv = r;
        if (piv != a) {
            for (int k2 = 0; k2 < nfree; ++k2) {
                long double t = M[a][k2]; M[a][k2] = M[piv][k2]; M[piv][k2] = t;
            }
            long double t = rhs[a]; rhs[a] = rhs[piv]; rhs[piv] = t;
        }
        long double d = M[a][a];
        if (fabsl(d) < 1e-30L) d = (d < 0 ? -1e-30L : 1e-30L);
        for (int r = a + 1; r < nfree; ++r) {
            long double f = M[r][a] / d;
            for (int k2 = a; k2 < nfree; ++k2) M[r][k2] -= f * M[a][k2];
            rhs[r] -= f * rhs[a];
        }
    }
    for (int a = nfree - 1; a >= 0; --a) {
        long double s = rhs[a];
        for (int k2 = a + 1; k2 < nfree; ++k2) s -= M[a][k2] * c[k2];
        long double d = M[a][a];
        if (fabsl(d) < 1e-30L) d = (d < 0 ? -1e-30L : 1e-30L);
        c[a] = s / d;
    }
}

struct TanhFit { unsigned c[PD + 1]; unsigned flag; };

static TanhFit fit_tanh_poly() {
    const long double S = 2.885390081777926814587L;   // 2*log2(e)
    const long double pxh = (long double)f16_to_f32h(f32_to_f16_rne(PX_F));
    const long double csh = (long double)f16_to_f32h(f32_to_f16_rne(CS_F));
    for (int i = 0; i < FIT_N; ++i) {
        long double th = 3.14159265358979323846L * (long double)i
                         / (2.0L * (FIT_N - 1));
        long double ww = pxh * sinl(th);          // w-domain samples
        g_xs[i] = ww;
        long double t = ww * csh;
        g_vs[i] = t * t - 1.0L;
        g_tg[i] = tanhl(ww / S);                  // tanh(s), s = w/S
    }
    long double c[PD + 1] = {};
    ls_solve(PD + 1, c);
    for (int j = PD; j >= 0; --j) {               // cascade f16 rounding
        c[j] = (long double)f16_to_f32h(f32_to_f16_rne((float)c[j]));
        if (j > 0) ls_solve(j, c);
    }
    TanhFit out;
    unsigned short hq[PD + 1];
    for (int j = 0; j <= PD; ++j) {
        hq[j] = f32_to_f16_rne((float)c[j]);
        out.c[j] = (unsigned)hq[j] | ((unsigned)hq[j] << 16);
    }
    // bit-exact sim of the device f16 pipeline, w in [-20,20] (s in [-6.9,6.9])
    long double cq[PD + 1];
    for (int j = 0; j <= PD; ++j) cq[j] = (long double)f16_to_f32h(hq[j]);
    auto r16 = [](long double v) -> long double {
        return (long double)f16_to_f32h(f32_to_f16_rne((float)v));
    };
    long double maxe = 0; bool bad = false;
    for (int i = -5120; i <= 5120; ++i) {
        long double w = (long double)i / 256.0L;
        long double sh = (long double)f16_to_f32h(f32_to_f16_rtz((float)w));
        long double xc = sh;
        if (xc > pxh) xc = pxh;
        if (xc < -pxh) xc = -pxh;
        long double tt = r16(xc * csh);
        long double vv = r16(tt * tt - 1.0L);
        long double p = cq[PD];
        for (int j = PD - 1; j >= 0; --j) p = r16(p * vv + cq[j]);
        long double kk = r16(xc * p);
        long double e = fabsl(kk - tanhl(w / S));
        if (!(e < 1.0L)) bad = true;
        if (e > maxe) maxe = e;
    }
    out.flag = (!bad && maxe <= 4.0e-3L) ? 0u : 1u;
    return out;
}

static const TanhFit g_tanh = fit_tanh_poly();    // pure CPU, at .so load

} // namespace

// ---------------------------------------------------------------------------

__device__ __forceinline__ unsigned pack_f16u(float a, float b) {
    return __builtin_bit_cast(unsigned, __builtin_amdgcn_cvt_pkrtz(a, b));
}
__device__ __forceinline__ half2v pack_f16h(float a, float b) {
    return __builtin_bit_cast(half2v, __builtin_amdgcn_cvt_pkrtz(a, b));
}

// Exchange: A' = {A.lo32, B.lo32}, B' = {A.hi32, B.hi32}  (lane halves).
__device__ __forceinline__ void xchg32(unsigned& A, unsigned& B, int lane) {
#if __has_builtin(__builtin_amdgcn_permlane32_swap)
    u32x2 r = __builtin_amdgcn_permlane32_swap(A, B, false, false);
    A = r[0];
    B = r[1];
#else
    unsigned Ax = (unsigned)__shfl_xor((int)A, 32, 64);
    unsigned Bx = (unsigned)__shfl_xor((int)B, 32, 64);
    bool lo = lane < 32;
    unsigned X = lo ? A : Bx;
    unsigned Y = lo ? Ax : B;
    A = X;
    B = Y;
#endif
}

__device__ __forceinline__ half8v make_frag(const unsigned* w) {
    u32x4 t; t[0] = w[0]; t[1] = w[1]; t[2] = w[2]; t[3] = w[3];
    return __builtin_bit_cast(half8v, t);
}

// Round-0 verified structure: each wave owns 32 batch x all 64 dims.
// State y (f32) in two 32x32 MFMA C-frags: dim = (r&3)+8*(r>>2)+4h (+32t),
// batch = lane&31.  Per f-eval: f16 arg pairs (v_pk_fma), word-swap via
// 8 permlane32_swap, 8 MFMAs with A = TANH_SCALE*Wf^T constant in registers,
// tanh on the scaled output w: poly (f16 Horner) or round-0 exp2 fallback.
__global__ __launch_bounds__(256, 2) void ode_rk4_kernel(
    const float* __restrict__ x,
    const float* __restrict__ W_in,  const float* __restrict__ b_in,
    const float* __restrict__ Wf,    const float* __restrict__ bf,
    const float* __restrict__ W_out, const float* __restrict__ b_out,
    float* __restrict__ out,
    unsigned tc0, unsigned tc1, unsigned tc2, unsigned tc3, unsigned tc4,
    unsigned tc5, unsigned tc6, unsigned tc7, unsigned tc8, unsigned tflag)
{
    const int tid  = threadIdx.x;
    const int wv   = tid >> 6;
    const int lane = tid & 63;
    const int b    = lane & 31;
    const int h    = lane >> 5;

    const int batch0 = (blockIdx.x * 4 + wv) * 32;
    const bool poly_ok = (tflag == 0u);

    // ---- constant A-frags: A[m][k] = TANH_SCALE * Wf[k][m], two M-tiles ----
    half8v a_wf0[4], a_wf1[4];
    #pragma unroll
    for (int q = 0; q < 4; ++q) {
        #pragma unroll
        for (int j = 0; j < 8; ++j) {
            int k = 16 * q + 8 * h + j;
            a_wf0[q][j] = (_Float16)(Wf[k * 64 + b]      * TANH_SCALE);
            a_wf1[q][j] = (_Float16)(Wf[k * 64 + 32 + b] * TANH_SCALE);
        }
    }
    // scaled bias in C-layout (free bias add as MFMA C-init)
    f32x16 bias0, bias1;
    #pragma unroll
    for (int r = 0; r < 16; ++r) {
        int row = (r & 3) + 8 * (r >> 2) + 4 * h;
        bias0[r] = bf[row]      * TANH_SCALE;
        bias1[r] = bf[32 + row] * TANH_SCALE;
    }

    // poly coefficients (kernarg scalars -> SGPR)
    const unsigned tcs[PD + 1] = {tc0, tc1, tc2, tc3, tc4, tc5, tc6, tc7, tc8};
    half2v Cf[PD + 1];
    #pragma unroll
    for (int j = 0; j <= PD; ++j) Cf[j] = __builtin_bit_cast(half2v, tcs[j]);
    const half2v hPX = {(_Float16)PX_F, (_Float16)PX_F};
    const half2v hNX = -hPX;
    const half2v hCS = {(_Float16)CS_F, (_Float16)CS_F};
    const half2v hM1 = {(_Float16)(-1.0f), (_Float16)(-1.0f)};
    const half2v hTWO = {(_Float16)2.0f, (_Float16)2.0f};

    // ---- input layer: Y0^T = W_in^T @ x^T + b_in (round-0 verbatim) ----
    f32x16 y0v, y1v;
    {
        const float* xp = x + (batch0 + b) * IN_DIM + 8 * h;
        float4 xa = *(const float4*)xp;
        float4 xc4 = *(const float4*)(xp + 4);
        u32x4 bw;
        bw[0] = pack_f16u(xa.x, xa.y);
        bw[1] = pack_f16u(xa.z, xa.w);
        bw[2] = pack_f16u(xc4.x, xc4.y);
        bw[3] = pack_f16u(xc4.z, xc4.w);
        half8v bx = __builtin_bit_cast(half8v, bw);

        half8v a0, a1;
        #pragma unroll
        for (int j = 0; j < 8; ++j) {
            int k = 8 * h + j;
            a0[j] = (_Float16)W_in[k * 64 + b];
            a1[j] = (_Float16)W_in[k * 64 + 32 + b];
        }
        f32x16 c0, c1;
        #pragma unroll
        for (int r = 0; r < 16; ++r) {
            int row = (r & 3) + 8 * (r >> 2) + 4 * h;
            c0[r] = b_in[row];
            c1[r] = b_in[32 + row];
        }
        y0v = __builtin_amdgcn_mfma_f32_32x32x16_f16(a0, bx, c0, 0, 0, 0);
        y1v = __builtin_amdgcn_mfma_f32_32x32x16_f16(a1, bx, c1, 0, 0, 0);
    }

    // word-swap (round-0 pattern) + frag assembly from 16 f16-pairs
    auto frags_from = [&](const half2v* wsrc, half8v* fb) {
        unsigned bw[16];
        #pragma unroll
        for (int i = 0; i < 16; ++i)
            bw[i] = __builtin_bit_cast(unsigned, wsrc[i]);
        #pragma unroll
        for (int t = 0; t < 2; ++t) {
            xchg32(bw[8 * t + 0], bw[8 * t + 2], lane);
            xchg32(bw[8 * t + 1], bw[8 * t + 3], lane);
            xchg32(bw[8 * t + 4], bw[8 * t + 6], lane);
            xchg32(bw[8 * t + 5], bw[8 * t + 7], lane);
        }
        #pragma unroll
        for (int q = 0; q < 4; ++q)
            fb[q] = make_frag(&bw[8 * (q >> 1) + 4 * (q & 1)]);
    };

    // f-eval: w = bias + A@B (C-layout, scaled);  k = tanh as f16 pairs in
    // C-layout pairing (pair l of tile t = regs 2l, 2l+1).
    auto feval = [&](const half8v* fb, half2v* ko) {
        f32x16 s0 = bias0, s1 = bias1;
        #pragma unroll
        for (int q = 0; q < 4; ++q) {
            s0 = __builtin_amdgcn_mfma_f32_32x32x16_f16(a_wf0[q], fb[q], s0, 0, 0, 0);
            s1 = __builtin_amdgcn_mfma_f32_32x32x16_f16(a_wf1[q], fb[q], s1, 0, 0, 0);
        }
        #pragma unroll
        for (int t = 0; t < 2; ++t) {
            const f32x16& sv = t ? s1 : s0;
            if (poly_ok) {
                #pragma unroll
                for (int l = 0; l < 8; ++l) {
                    half2v wh = pack_f16h(sv[2 * l], sv[2 * l + 1]);
                    half2v xc = __builtin_elementwise_min(
                                    __builtin_elementwise_max(wh, hNX), hPX);
                    half2v tt = xc * hCS;
                    half2v vv = __builtin_elementwise_fma(tt, tt, hM1);
                    half2v p  = Cf[PD];
                    #pragma unroll
                    for (int j = PD - 1; j >= 0; --j)
                        p = __builtin_elementwise_fma(p, vv, Cf[j]);
                    ko[8 * t + l] = xc * p;
                }
            } else {
                // round-0 proven path: w is already the exp2 argument
                #pragma unroll
                for (int l = 0; l < 8; ++l) {
                    float e0 = __builtin_amdgcn_exp2f(sv[2 * l]);
                    float e1 = __builtin_amdgcn_exp2f(sv[2 * l + 1]);
                    float k0 = __builtin_fmaf(-2.0f, __builtin_amdgcn_rcpf(e0 + 1.0f), 1.0f);
                    float k1 = __builtin_fmaf(-2.0f, __builtin_amdgcn_rcpf(e1 + 1.0f), 1.0f);
                    ko[8 * t + l] = pack_f16h(k0, k1);
                }
            }
        }
    };

    const float dt  = 1.0f / N_STEPS;
    const float c16 = dt / 6.0f;
    const half2v chv  = {(_Float16)(0.5f * dt), (_Float16)(0.5f * dt)}; // 2^-6
    const half2v cdtv = {(_Float16)dt, (_Float16)dt};                   // 2^-5

    #pragma unroll 1
    for (int st = 0; st < N_STEPS; ++st) {
        // y packed to f16 pairs once per step (C-layout pairing)
        half2v yh[16];
        #pragma unroll
        for (int t = 0; t < 2; ++t) {
            const f32x16& yy = t ? y1v : y0v;
            #pragma unroll
            for (int l = 0; l < 8; ++l)
                yh[8 * t + l] = pack_f16h(yy[2 * l], yy[2 * l + 1]);
        }

        half8v fb[4];
        half2v kcur[16], ksh[16], argw[16];

        frags_from(yh, fb);                       // arg1 = y
        feval(fb, kcur);                          // k1
        #pragma unroll
        for (int i = 0; i < 16; ++i) ksh[i] = kcur[i];

        #pragma unroll
        for (int i = 0; i < 16; ++i)              // arg2 = y + dt/2 * k1
            argw[i] = __builtin_elementwise_fma(chv, kcur[i], yh[i]);
        frags_from(argw, fb);
        feval(fb, kcur);                          // k2
        #pragma unroll
        for (int i = 0; i < 16; ++i)
            ksh[i] = __builtin_elementwise_fma(hTWO, kcur[i], ksh[i]);

        #pragma unroll
        for (int i = 0; i < 16; ++i)              // arg3 = y + dt/2 * k2
            argw[i] = __builtin_elementwise_fma(chv, kcur[i], yh[i]);
        frags_from(argw, fb);
        feval(fb, kcur);                          // k3
        #pragma unroll
        for (int i = 0; i < 16; ++i)
            ksh[i] = __builtin_elementwise_fma(hTWO, kcur[i], ksh[i]);

        #pragma unroll
        for (int i = 0; i < 16; ++i)              // arg4 = y + dt * k3
            argw[i] = __builtin_elementwise_fma(cdtv, kcur[i], yh[i]);
        frags_from(argw, fb);
        feval(fb, kcur);                          // k4
        #pragma unroll
        for (int i = 0; i < 16; ++i)
            ksh[i] = ksh[i] + kcur[i];

        // y += dt/6 * (k1 + 2k2 + 2k3 + k4)
        #pragma unroll
        for (int t = 0; t < 2; ++t) {
            f32x16& yy = t ? y1v : y0v;
            #pragma unroll
            for (int l = 0; l < 8; ++l) {
                half2v kk = ksh[8 * t + l];
                yy[2 * l]     = __builtin_fmaf(c16, (float)kk[0], yy[2 * l]);
                yy[2 * l + 1] = __builtin_fmaf(c16, (float)kk[1], yy[2 * l + 1]);
            }
        }
    }

    // ---- readout: out^T = W_out^T @ y1^T + b_out (round-0 verbatim) ----
    {
        half2v yh[16];
        #pragma unroll
        for (int t = 0; t < 2; ++t) {
            const f32x16& yy = t ? y1v : y0v;
            #pragma unroll
            for (int l = 0; l < 8; ++l)
                yh[8 * t + l] = pack_f16h(yy[2 * l], yy[2 * l + 1]);
        }
        half8v fb[4];
        frags_from(yh, fb);

        half8v a_wo[4];
        #pragma unroll
        for (int q = 0; q < 4; ++q) {
            #pragma unroll
            for (int j = 0; j < 8; ++j) {
                int k = 16 * q + 8 * h + j;
                a_wo[q][j] = (b < OUT_DIM) ? (_Float16)W_out[k * OUT_DIM + b]
                                           : (_Float16)0.0f;
            }
        }
        f32x16 so;
        #pragma unroll
        for (int r = 0; r < 16; ++r) {
            int o = (r & 3) + 8 * (r >> 2) + 4 * h;
            so[r] = (r < 8) ? b_out[o] : 0.0f;
        }
        #pragma unroll
        for (int q = 0; q < 4; ++q)
            so = __builtin_amdgcn_mfma_f32_32x32x16_f16(a_wo[q], fb[q], so, 0, 0, 0);

        float* op = out + (batch0 + b) * OUT_DIM;
        *(float4*)(op + 4 * h)     = make_float4(so[0], so[1], so[2], so[3]);
        *(float4*)(op + 8 + 4 * h) = make_float4(so[4], so[5], so[6], so[7]);
    }
}

extern "C" void kernel_launch(void* const* d_in, const int* in_sizes, int n_in,
                              void* d_out, int out_size, void* d_ws, size_t ws_size,
                              hipStream_t stream) {
    const float* x     = (const float*)d_in[0];
    const float* W_in  = (const float*)d_in[1];
    const float* b_in  = (const float*)d_in[2];
    const float* Wf    = (const float*)d_in[3];
    const float* bf    = (const float*)d_in[4];
    const float* W_out = (const float*)d_in[5];
    const float* b_out = (const float*)d_in[6];
    float* outp        = (float*)d_out;

    dim3 grid(BATCH / 128);   // 4 waves/block, 32 batch per wave, no LDS
    dim3 block(256);
    hipLaunchKernelGGL(ode_rk4_kernel, grid, block, 0, stream,
                       x, W_in, b_in, Wf, bf, W_out, b_out, outp,
                       g_tanh.c[0], g_tanh.c[1], g_tanh.c[2], g_tanh.c[3],
                       g_tanh.c[4], g_tanh.c[5], g_tanh.c[6], g_tanh.c[7],
                       g_tanh.c[8], g_tanh.flag);
}

// Round 5
// 2343.489 us; speedup vs baseline: 1.0646x; 1.0646x over previous
//
#include <hip/hip_runtime.h>
#include <cmath>

#define BATCH    1048576
#define IN_DIM   16
#define ODE_DIM  64
#define OUT_DIM  16
#define N_STEPS  32

typedef _Float16 half2v __attribute__((ext_vector_type(2)));
typedef _Float16 half8v __attribute__((ext_vector_type(8)));
typedef float    f32x16 __attribute__((ext_vector_type(16)));
typedef unsigned u32x2  __attribute__((ext_vector_type(2)));
typedef unsigned u32x4  __attribute__((ext_vector_type(4)));

// 2*log2(e): MFMA output w = TANH_SCALE * s is the exp2 argument of the
// fallback tanh and the poly-tanh input domain.
#define TANH_SCALE 2.8853900817779268f

// ---------------------------------------------------------------------------
// t-domain poly tanh:  w = TANH_SCALE*s;  xc = clamp(w,-PX,PX);  t = xc*CS
// (|t| <= 1.414);  v = t^2 - 1 in [-1, ~0.998];  k = t * R(v), R degree PD.
// Fit host-side: unit-weight LS in k-space (basis t*v^j) at Chebyshev-in-w
// nodes, long double; cascade-round coeffs to f16 with refit.  Bit-exact
// device-pipeline sim gates at 3e-2 (NaN/blowup insurance only); flag=1
// selects the separately-compiled exp2+rcp kernel (round-0 proven).
// ---------------------------------------------------------------------------
#define PD 8
#define PX_F 11.83f      // TANH_SCALE * 4.1
#define CS_F 0.119507f   // ~= sqrt(2)/f16(PX_F): t_max ~= 1.4136, v_max<1

namespace {

static unsigned short f32_to_f16_rne(float ff) {
    unsigned u = __builtin_bit_cast(unsigned, ff);
    unsigned sign = (u >> 16) & 0x8000u;
    int exp = (int)((u >> 23) & 0xFF) - 127 + 15;
    unsigned man = u & 0x7FFFFFu;
    if (exp >= 31) return (unsigned short)(sign | 0x7C00u);
    if (exp <= 0) {
        if (exp < -10) return (unsigned short)sign;
        man |= 0x800000u;
        int shift = 14 - exp;
        unsigned half = man >> shift;
        unsigned rem  = man & ((1u << shift) - 1u);
        unsigned mid  = 1u << (shift - 1);
        if (rem > mid || (rem == mid && (half & 1u))) half++;
        return (unsigned short)(sign | half);
    }
    unsigned half = ((unsigned)exp << 10) | (man >> 13);
    unsigned rem = man & 0x1FFFu;
    if (rem > 0x1000u || (rem == 0x1000u && (half & 1u))) half++;
    return (unsigned short)(sign | half);
}

static unsigned short f32_to_f16_rtz(float ff) {   // chop (matches cvt_pkrtz)
    unsigned u = __builtin_bit_cast(unsigned, ff);
    unsigned sign = (u >> 16) & 0x8000u;
    unsigned e8 = (u >> 23) & 0xFFu;
    unsigned man = u & 0x7FFFFFu;
    if (e8 == 0xFFu) return (unsigned short)(sign | 0x7C00u | (man ? 0x200u : 0u));
    int exp = (int)e8 - 127 + 15;
    if (exp >= 31) return (unsigned short)(sign | 0x7BFFu);
    if (exp <= 0) {
        if (exp < -10) return (unsigned short)sign;
        man |= 0x800000u;
        return (unsigned short)(sign | (man >> (14 - exp)));
    }
    return (unsigned short)(sign | ((unsigned)exp << 10) | (man >> 13));
}

static float f16_to_f32h(unsigned short h) {
    unsigned sign = ((unsigned)h & 0x8000u) << 16;
    unsigned exp = (h >> 10) & 0x1Fu;
    unsigned man = h & 0x3FFu;
    unsigned u;
    if (exp == 0) {
        if (!man) u = sign;
        else {
            int e = -1;
            do { man <<= 1; ++e; } while (!(man & 0x400u));
            u = sign | ((unsigned)(127 - 15 - e) << 23) | ((man & 0x3FFu) << 13);
        }
    } else if (exp == 31) u = sign | 0x7F800000u | (man << 13);
    else u = sign | ((exp - 15 + 127) << 23) | (man << 13);
    return __builtin_bit_cast(float, u);
}

constexpr int FIT_N = 2001;
static long double g_ts[FIT_N], g_vs[FIT_N], g_tg[FIT_N];

// Unit-weight LS (k-space): minimize sum_i (t_i * sum_j c_j v_i^j - tg_i)^2
// for c[0..nfree-1] with c[nfree..PD] held fixed.
static void ls_solve(int nfree, long double* c) {
    long double M[PD + 1][PD + 1] = {};
    long double rhs[PD + 1] = {};
    for (int i = 0; i < FIT_N; ++i) {
        long double pj[PD + 1];
        pj[0] = 1.0L;
        for (int j = 1; j <= PD; ++j) pj[j] = pj[j - 1] * g_vs[i];
        long double resid = g_tg[i];
        for (int j = nfree; j <= PD; ++j) resid -= g_ts[i] * pj[j] * c[j];
        for (int a = 0; a < nfree; ++a) {
            long double ba = g_ts[i] * pj[a];
            for (int b2 = 0; b2 < nfree; ++b2) M[a][b2] += ba * g_ts[i] * pj[b2];
            rhs[a] += ba * resid;
        }
    }
    for (int a = 0; a < nfree; ++a) {
        int piv = a;
        for (int r = a + 1; r < nfree; ++r)
            if (fabsl(M[r][a]) > fabsl(M[piv][a])) piv = r;
        if (piv != a) {
            for (int k2 = 0; k2 < nfree; ++k2) {
                long double t = M[a][k2]; M[a][k2] = M[piv][k2]; M[piv][k2] = t;
            }
            long double t = rhs[a]; rhs[a] = rhs[piv]; rhs[piv] = t;
        }
        long double d = M[a][a];
        if (fabsl(d) < 1e-30L) d = (d < 0 ? -1e-30L : 1e-30L);
        for (int r = a + 1; r < nfree; ++r) {
            long double f = M[r][a] / d;
            for (int k2 = a; k2 < nfree; ++k2) M[r][k2] -= f * M[a][k2];
            rhs[r] -= f * rhs[a];
        }
    }
    for (int a = nfree - 1; a >= 0; --a) {
        long double s = rhs[a];
        for (int k2 = a + 1; k2 < nfree; ++k2) s -= M[a][k2] * c[k2];
        long double d = M[a][a];
        if (fabsl(d) < 1e-30L) d = (d < 0 ? -1e-30L : 1e-30L);
        c[a] = s / d;
    }
}

struct TanhFit { unsigned c[PD + 1]; unsigned flag; };

static TanhFit fit_tanh_poly() {
    const long double S = 2.885390081777926814587L;   // 2*log2(e)
    const long double pxh = (long double)f16_to_f32h(f32_to_f16_rne(PX_F));
    const long double csh = (long double)f16_to_f32h(f32_to_f16_rne(CS_F));
    for (int i = 0; i < FIT_N; ++i) {
        long double th = 3.14159265358979323846L * (long double)i
                         / (2.0L * (FIT_N - 1));
        long double ww = pxh * sinl(th);          // w in [0, pxh]
        long double t  = ww * csh;
        g_ts[i] = t;
        g_vs[i] = t * t - 1.0L;
        g_tg[i] = tanhl(ww / S);
    }
    long double c[PD + 1] = {};
    ls_solve(PD + 1, c);
    for (int j = PD; j >= 0; --j) {               // cascade f16 rounding
        c[j] = (long double)f16_to_f32h(f32_to_f16_rne((float)c[j]));
        if (j > 0) ls_solve(j, c);
    }
    TanhFit out;
    unsigned short hq[PD + 1];
    for (int j = 0; j <= PD; ++j) {
        hq[j] = f32_to_f16_rne((float)c[j]);
        out.c[j] = (unsigned)hq[j] | ((unsigned)hq[j] << 16);
    }
    // bit-exact sim of device f16 pipeline, w in [-20,20] (s in [-6.9,6.9])
    long double cq[PD + 1];
    for (int j = 0; j <= PD; ++j) cq[j] = (long double)f16_to_f32h(hq[j]);
    auto r16 = [](long double v) -> long double {
        return (long double)f16_to_f32h(f32_to_f16_rne((float)v));
    };
    long double maxe = 0; bool bad = false;
    for (int i = -5120; i <= 5120; ++i) {
        long double w = (long double)i / 256.0L;
        long double wh = (long double)f16_to_f32h(f32_to_f16_rtz((float)w));
        long double xc = wh;
        if (xc > pxh) xc = pxh;
        if (xc < -pxh) xc = -pxh;
        long double tt = r16(xc * csh);
        long double vv = r16(tt * tt - 1.0L);
        long double p = cq[PD];
        for (int j = PD - 1; j >= 0; --j) p = r16(p * vv + cq[j]);
        long double kk = r16(tt * p);
        long double e = fabsl(kk - tanhl(w / S));
        if (!(e < 1.0L)) bad = true;
        if (e > maxe) maxe = e;
    }
    out.flag = (!bad && maxe <= 3.0e-2L) ? 0u : 1u;  // insurance gate only
    return out;
}

static const TanhFit g_tanh = fit_tanh_poly();    // pure CPU, at .so load

} // namespace

// ---------------------------------------------------------------------------

__device__ __forceinline__ unsigned pack_f16u(float a, float b) {
    return __builtin_bit_cast(unsigned, __builtin_amdgcn_cvt_pkrtz(a, b));
}
__device__ __forceinline__ half2v pack_f16h(float a, float b) {
    return __builtin_bit_cast(half2v, __builtin_amdgcn_cvt_pkrtz(a, b));
}

// Exchange: A' = {A.lo32, B.lo32}, B' = {A.hi32, B.hi32}  (lane halves).
__device__ __forceinline__ void xchg32(unsigned& A, unsigned& B, int lane) {
#if __has_builtin(__builtin_amdgcn_permlane32_swap)
    u32x2 r = __builtin_amdgcn_permlane32_swap(A, B, false, false);
    A = r[0];
    B = r[1];
#else
    unsigned Ax = (unsigned)__shfl_xor((int)A, 32, 64);
    unsigned Bx = (unsigned)__shfl_xor((int)B, 32, 64);
    bool lo = lane < 32;
    unsigned X = lo ? A : Bx;
    unsigned Y = lo ? Ax : B;
    A = X;
    B = Y;
#endif
}

__device__ __forceinline__ half8v make_frag(const unsigned* w) {
    u32x4 t; t[0] = w[0]; t[1] = w[1]; t[2] = w[2]; t[3] = w[3];
    return __builtin_bit_cast(half8v, t);
}

// Round-0 verified structure: each wave owns 32 batch x all 64 dims.
// State y (f32) in two 32x32 MFMA C-frags: dim = (r&3)+8*(r>>2)+4h (+32t),
// batch = lane&31.  Per f-eval: f16 arg pairs (v_pk_fma), word-swap via
// 8 permlane32_swap, 8 MFMAs with A = TANH_SCALE*Wf^T constant in registers.
// POLY=true: t-domain f16-pk polynomial tanh.  POLY=false: exp2+rcp (proven).
// Twin instantiations, selected host-side -> no device branch.
template <bool POLY>
__global__ __launch_bounds__(256, 2) void ode_rk4_kernel(
    const float* __restrict__ x,
    const float* __restrict__ W_in,  const float* __restrict__ b_in,
    const float* __restrict__ Wf,    const float* __restrict__ bf,
    const float* __restrict__ W_out, const float* __restrict__ b_out,
    float* __restrict__ out,
    unsigned tc0, unsigned tc1, unsigned tc2, unsigned tc3, unsigned tc4,
    unsigned tc5, unsigned tc6, unsigned tc7, unsigned tc8)
{
    const int tid  = threadIdx.x;
    const int wv   = tid >> 6;
    const int lane = tid & 63;
    const int b    = lane & 31;
    const int h    = lane >> 5;

    const int batch0 = (blockIdx.x * 4 + wv) * 32;

    // ---- constant A-frags: A[m][k] = TANH_SCALE * Wf[k][m], two M-tiles ----
    half8v a_wf0[4], a_wf1[4];
    #pragma unroll
    for (int q = 0; q < 4; ++q) {
        #pragma unroll
        for (int j = 0; j < 8; ++j) {
            int k = 16 * q + 8 * h + j;
            a_wf0[q][j] = (_Float16)(Wf[k * 64 + b]      * TANH_SCALE);
            a_wf1[q][j] = (_Float16)(Wf[k * 64 + 32 + b] * TANH_SCALE);
        }
    }
    // scaled bias in C-layout (free bias add as MFMA C-init)
    f32x16 bias0, bias1;
    #pragma unroll
    for (int r = 0; r < 16; ++r) {
        int row = (r & 3) + 8 * (r >> 2) + 4 * h;
        bias0[r] = bf[row]      * TANH_SCALE;
        bias1[r] = bf[32 + row] * TANH_SCALE;
    }

    // poly coefficients (kernarg scalars -> SGPR)
    const unsigned tcs[PD + 1] = {tc0, tc1, tc2, tc3, tc4, tc5, tc6, tc7, tc8};
    half2v Cf[PD + 1];
    #pragma unroll
    for (int j = 0; j <= PD; ++j) Cf[j] = __builtin_bit_cast(half2v, tcs[j]);
    const half2v hPX = {(_Float16)PX_F, (_Float16)PX_F};
    const half2v hNX = -hPX;
    const half2v hCS = {(_Float16)CS_F, (_Float16)CS_F};
    const half2v hM1 = {(_Float16)(-1.0f), (_Float16)(-1.0f)};
    const half2v hTWO = {(_Float16)2.0f, (_Float16)2.0f};

    // ---- input layer: Y0^T = W_in^T @ x^T + b_in ----
    f32x16 y0v, y1v;
    {
        const float* xp = x + (batch0 + b) * IN_DIM + 8 * h;
        float4 xa = *(const float4*)xp;
        float4 xc4 = *(const float4*)(xp + 4);
        u32x4 bw;
        bw[0] = pack_f16u(xa.x, xa.y);
        bw[1] = pack_f16u(xa.z, xa.w);
        bw[2] = pack_f16u(xc4.x, xc4.y);
        bw[3] = pack_f16u(xc4.z, xc4.w);
        half8v bx = __builtin_bit_cast(half8v, bw);

        half8v a0, a1;
        #pragma unroll
        for (int j = 0; j < 8; ++j) {
            int k = 8 * h + j;
            a0[j] = (_Float16)W_in[k * 64 + b];
            a1[j] = (_Float16)W_in[k * 64 + 32 + b];
        }
        f32x16 c0, c1;
        #pragma unroll
        for (int r = 0; r < 16; ++r) {
            int row = (r & 3) + 8 * (r >> 2) + 4 * h;
            c0[r] = b_in[row];
            c1[r] = b_in[32 + row];
        }
        y0v = __builtin_amdgcn_mfma_f32_32x32x16_f16(a0, bx, c0, 0, 0, 0);
        y1v = __builtin_amdgcn_mfma_f32_32x32x16_f16(a1, bx, c1, 0, 0, 0);
    }

    // word-swap + frag assembly from 16 f16-pairs (C-layout pairing)
    auto frags_from = [&](const half2v* wsrc, half8v* fb) {
        unsigned bw[16];
        #pragma unroll
        for (int i = 0; i < 16; ++i)
            bw[i] = __builtin_bit_cast(unsigned, wsrc[i]);
        #pragma unroll
        for (int t = 0; t < 2; ++t) {
            xchg32(bw[8 * t + 0], bw[8 * t + 2], lane);
            xchg32(bw[8 * t + 1], bw[8 * t + 3], lane);
            xchg32(bw[8 * t + 4], bw[8 * t + 6], lane);
            xchg32(bw[8 * t + 5], bw[8 * t + 7], lane);
        }
        #pragma unroll
        for (int q = 0; q < 4; ++q)
            fb[q] = make_frag(&bw[8 * (q >> 1) + 4 * (q & 1)]);
    };

    // f-eval: w = bias + A@B (C-layout, scaled);  k = tanh(w/S) as f16 pairs.
    auto feval = [&](const half8v* fb, half2v* ko) {
        f32x16 s0 = bias0, s1 = bias1;
        #pragma unroll
        for (int q = 0; q < 4; ++q) {
            s0 = __builtin_amdgcn_mfma_f32_32x32x16_f16(a_wf0[q], fb[q], s0, 0, 0, 0);
            s1 = __builtin_amdgcn_mfma_f32_32x32x16_f16(a_wf1[q], fb[q], s1, 0, 0, 0);
        }
        #pragma unroll
        for (int t = 0; t < 2; ++t) {
            const f32x16& sv = t ? s1 : s0;
            #pragma unroll
            for (int l = 0; l < 8; ++l) {
                if constexpr (POLY) {
                    half2v wh = pack_f16h(sv[2 * l], sv[2 * l + 1]);
                    half2v xc = __builtin_elementwise_min(
                                    __builtin_elementwise_max(wh, hNX), hPX);
                    half2v tt = xc * hCS;
                    half2v vv = __builtin_elementwise_fma(tt, tt, hM1);
                    half2v p  = Cf[PD];
                    #pragma unroll
                    for (int j = PD - 1; j >= 0; --j)
                        p = __builtin_elementwise_fma(p, vv, Cf[j]);
                    ko[8 * t + l] = tt * p;
                } else {
                    float e0 = __builtin_amdgcn_exp2f(sv[2 * l]);
                    float e1 = __builtin_amdgcn_exp2f(sv[2 * l + 1]);
                    float k0 = __builtin_fmaf(-2.0f, __builtin_amdgcn_rcpf(e0 + 1.0f), 1.0f);
                    float k1 = __builtin_fmaf(-2.0f, __builtin_amdgcn_rcpf(e1 + 1.0f), 1.0f);
                    ko[8 * t + l] = pack_f16h(k0, k1);
                }
            }
        }
    };

    const float dt  = 1.0f / N_STEPS;
    const float c16 = dt / 6.0f;
    const half2v chv  = {(_Float16)(0.5f * dt), (_Float16)(0.5f * dt)}; // 2^-6
    const half2v cdtv = {(_Float16)dt, (_Float16)dt};                   // 2^-5

    #pragma unroll 1
    for (int st = 0; st < N_STEPS; ++st) {
        // y packed to f16 pairs once per step (C-layout pairing)
        half2v yh[16];
        #pragma unroll
        for (int t = 0; t < 2; ++t) {
            const f32x16& yy = t ? y1v : y0v;
            #pragma unroll
            for (int l = 0; l < 8; ++l)
                yh[8 * t + l] = pack_f16h(yy[2 * l], yy[2 * l + 1]);
        }

        half8v fb[4];
        half2v kcur[16], ksh[16], argw[16];

        frags_from(yh, fb);                       // arg1 = y
        feval(fb, kcur);                          // k1
        #pragma unroll
        for (int i = 0; i < 16; ++i) ksh[i] = kcur[i];

        #pragma unroll
        for (int i = 0; i < 16; ++i)              // arg2 = y + dt/2 * k1
            argw[i] = __builtin_elementwise_fma(chv, kcur[i], yh[i]);
        frags_from(argw, fb);
        feval(fb, kcur);                          // k2
        #pragma unroll
        for (int i = 0; i < 16; ++i)
            ksh[i] = __builtin_elementwise_fma(hTWO, kcur[i], ksh[i]);

        #pragma unroll
        for (int i = 0; i < 16; ++i)              // arg3 = y + dt/2 * k2
            argw[i] = __builtin_elementwise_fma(chv, kcur[i], yh[i]);
        frags_from(argw, fb);
        feval(fb, kcur);                          // k3
        #pragma unroll
        for (int i = 0; i < 16; ++i)
            ksh[i] = __builtin_elementwise_fma(hTWO, kcur[i], ksh[i]);

        #pragma unroll
        for (int i = 0; i < 16; ++i)              // arg4 = y + dt * k3
            argw[i] = __builtin_elementwise_fma(cdtv, kcur[i], yh[i]);
        frags_from(argw, fb);
        feval(fb, kcur);                          // k4
        #pragma unroll
        for (int i = 0; i < 16; ++i)
            ksh[i] = ksh[i] + kcur[i];

        // y += dt/6 * (k1 + 2k2 + 2k3 + k4)
        #pragma unroll
        for (int t = 0; t < 2; ++t) {
            f32x16& yy = t ? y1v : y0v;
            #pragma unroll
            for (int l = 0; l < 8; ++l) {
                half2v kk = ksh[8 * t + l];
                yy[2 * l]     = __builtin_fmaf(c16, (float)kk[0], yy[2 * l]);
                yy[2 * l + 1] = __builtin_fmaf(c16, (float)kk[1], yy[2 * l + 1]);
            }
        }
    }

    // ---- readout: out^T = W_out^T @ y1^T + b_out ----
    {
        half2v yh[16];
        #pragma unroll
        for (int t = 0; t < 2; ++t) {
            const f32x16& yy = t ? y1v : y0v;
            #pragma unroll
            for (int l = 0; l < 8; ++l)
                yh[8 * t + l] = pack_f16h(yy[2 * l], yy[2 * l + 1]);
        }
        half8v fb[4];
        frags_from(yh, fb);

        half8v a_wo[4];
        #pragma unroll
        for (int q = 0; q < 4; ++q) {
            #pragma unroll
            for (int j = 0; j < 8; ++j) {
                int k = 16 * q + 8 * h + j;
                a_wo[q][j] = (b < OUT_DIM) ? (_Float16)W_out[k * OUT_DIM + b]
                                           : (_Float16)0.0f;
            }
        }
        f32x16 so;
        #pragma unroll
        for (int r = 0; r < 16; ++r) {
            int o = (r & 3) + 8 * (r >> 2) + 4 * h;
            so[r] = (r < 8) ? b_out[o] : 0.0f;
        }
        #pragma unroll
        for (int q = 0; q < 4; ++q)
            so = __builtin_amdgcn_mfma_f32_32x32x16_f16(a_wo[q], fb[q], so, 0, 0, 0);

        float* op = out + (batch0 + b) * OUT_DIM;
        *(float4*)(op + 4 * h)     = make_float4(so[0], so[1], so[2], so[3]);
        *(float4*)(op + 8 + 4 * h) = make_float4(so[4], so[5], so[6], so[7]);
    }
}

extern "C" void kernel_launch(void* const* d_in, const int* in_sizes, int n_in,
                              void* d_out, int out_size, void* d_ws, size_t ws_size,
                              hipStream_t stream) {
    const float* x     = (const float*)d_in[0];
    const float* W_in  = (const float*)d_in[1];
    const float* b_in  = (const float*)d_in[2];
    const float* Wf    = (const float*)d_in[3];
    const float* bf    = (const float*)d_in[4];
    const float* W_out = (const float*)d_in[5];
    const float* b_out = (const float*)d_in[6];
    float* outp        = (float*)d_out;

    dim3 grid(BATCH / 128);   // 4 waves/block, 32 batch per wave, no LDS
    dim3 block(256);
    if (g_tanh.flag == 0u) {
        hipLaunchKernelGGL((ode_rk4_kernel<true>), grid, block, 0, stream,
                           x, W_in, b_in, Wf, bf, W_out, b_out, outp,
                           g_tanh.c[0], g_tanh.c[1], g_tanh.c[2], g_tanh.c[3],
                           g_tanh.c[4], g_tanh.c[5], g_tanh.c[6], g_tanh.c[7],
                           g_tanh.c[8]);
    } else {
        hipLaunchKernelGGL((ode_rk4_kernel<false>), grid, block, 0, stream,
                           x, W_in, b_in, Wf, bf, W_out, b_out, outp,
                           g_tanh.c[0], g_tanh.c[1], g_tanh.c[2], g_tanh.c[3],
                           g_tanh.c[4], g_tanh.c[5], g_tanh.c[6], g_tanh.c[7],
                           g_tanh.c[8]);
    }
}